// Round 1
// baseline (1691.446 us; speedup 1.0000x reference)
//
#include <hip/hip_runtime.h>
#include <math.h>

#define BN 2
#define SN 1024
#define NTOK 2048      // BN*SN
#define DDIM 1024
#define HDIM 2048
#define NE 8
#define TOPK 2
#define EPS_RMS 1e-5f
#define EPS_TOPK 1e-10f

#define TM 64
#define TH 64
#define DK 16

// ---------------- Kernel 1: RMSNorm + router + top-2 scatter ----------------
__global__ void k_norm_router(const float* __restrict__ x,
                              const float* __restrict__ g,
                              const float* __restrict__ gate_w,
                              float* __restrict__ x_norm,
                              int* __restrict__ counts,
                              int* __restrict__ slot_token,
                              float* __restrict__ slot_prob) {
    int token = blockIdx.x;
    int tid = threadIdx.x;
    int lane = tid & 63;
    int wave = tid >> 6;

    __shared__ float xs[DDIM];    // 4 KB
    __shared__ float red[8];
    __shared__ float lr[4][NE];

    const float* xrow = x + (size_t)token * DDIM;
    float v[4];
    float ss = 0.f;
    #pragma unroll
    for (int i = 0; i < 4; i++) {
        float val = xrow[tid + i * 256];
        v[i] = val;
        ss += val * val;
    }
    #pragma unroll
    for (int off = 32; off > 0; off >>= 1) ss += __shfl_down(ss, off, 64);
    if (lane == 0) red[wave] = ss;
    __syncthreads();
    if (tid == 0) {
        float s = red[0] + red[1] + red[2] + red[3];
        red[0] = rsqrtf(s / (float)DDIM + EPS_RMS);
    }
    __syncthreads();
    float scale = red[0];
    #pragma unroll
    for (int i = 0; i < 4; i++) {
        int d = tid + i * 256;
        float xn = v[i] * scale * g[d];
        xs[d] = xn;
        x_norm[(size_t)token * DDIM + d] = xn;
    }
    __syncthreads();

    // router logits: 8 dot products of length D
    float part[NE];
    #pragma unroll
    for (int e = 0; e < NE; e++) part[e] = 0.f;
    for (int d = tid; d < DDIM; d += 256) {
        float xv = xs[d];
        #pragma unroll
        for (int e = 0; e < NE; e++) part[e] += xv * gate_w[e * DDIM + d];
    }
    #pragma unroll
    for (int e = 0; e < NE; e++) {
        #pragma unroll
        for (int off = 32; off > 0; off >>= 1) part[e] += __shfl_down(part[e], off, 64);
    }
    if (lane == 0) {
        #pragma unroll
        for (int e = 0; e < NE; e++) lr[wave][e] = part[e];
    }
    __syncthreads();
    if (tid == 0) {
        float logits[NE];
        #pragma unroll
        for (int e = 0; e < NE; e++)
            logits[e] = lr[0][e] + lr[1][e] + lr[2][e] + lr[3][e];
        float mx = logits[0];
        #pragma unroll
        for (int e = 1; e < NE; e++) mx = fmaxf(mx, logits[e]);
        float p[NE];
        float Z = 0.f;
        #pragma unroll
        for (int e = 0; e < NE; e++) { p[e] = expf(logits[e] - mx); Z += p[e]; }
        #pragma unroll
        for (int e = 0; e < NE; e++) p[e] /= Z;
        // top-2, first-occurrence wins on ties (matches jax.lax.top_k)
        int i1 = 0;
        #pragma unroll
        for (int e = 1; e < NE; e++) if (p[e] > p[i1]) i1 = e;
        int i2 = (i1 == 0) ? 1 : 0;
        #pragma unroll
        for (int e = 0; e < NE; e++) if (e != i1 && p[e] > p[i2] && e != i2) {
            if (e < i2 || p[e] > p[i2]) i2 = e;
        }
        // recompute i2 cleanly (strict-> keeps lowest index among equals)
        i2 = -1;
        #pragma unroll
        for (int e = 0; e < NE; e++) {
            if (e == i1) continue;
            if (i2 < 0 || p[e] > p[i2]) i2 = e;
        }
        float denom = p[i1] + p[i2] + EPS_TOPK;
        int pos1 = atomicAdd(&counts[i1], 1);
        slot_token[i1 * NTOK + pos1] = token;
        slot_prob[i1 * NTOK + pos1] = p[i1] / denom;
        int pos2 = atomicAdd(&counts[i2], 1);
        slot_token[i2 * NTOK + pos2] = token;
        slot_prob[i2 * NTOK + pos2] = p[i2] / denom;
    }
}

// ---------------- Kernel 2: per-expert GEMM h1,h2 + SiLU ----------------
// grid: (H/TH, NTOK/TM capacity, NE), block 256
__global__ void k_ffn_h(const float* __restrict__ x_norm,
                        const float* __restrict__ w1,
                        const float* __restrict__ w2,
                        const int* __restrict__ counts,
                        const int* __restrict__ slot_token,
                        float* __restrict__ hidden) {
    int e = blockIdx.z;
    int cnt = counts[e];
    int m0 = blockIdx.y * TM;
    if (m0 >= cnt) return;
    int h0 = blockIdx.x * TH;
    int off = 0;
    for (int i = 0; i < e; i++) off += counts[i];

    int tid = threadIdx.x;
    int j = tid & 63;       // h column within tile
    int i0 = tid >> 6;      // 0..3 row group

    __shared__ float xsh[TM][DK];   // 4 KB
    __shared__ int tok[TM];

    if (tid < TM) {
        int idx = m0 + tid;
        tok[tid] = (idx < cnt) ? slot_token[e * NTOK + idx] : -1;
    }

    float acc1[16], acc2[16];
    #pragma unroll
    for (int r = 0; r < 16; r++) { acc1[r] = 0.f; acc2[r] = 0.f; }

    const float* w1p = w1 + (size_t)e * DDIM * HDIM;
    const float* w2p = w2 + (size_t)e * DDIM * HDIM;

    for (int d0 = 0; d0 < DDIM; d0 += DK) {
        __syncthreads();
        for (int t = tid; t < TM * DK; t += 256) {
            int row = t / DK, col = t % DK;
            int tk = tok[row];
            xsh[row][col] = (tk >= 0) ? x_norm[(size_t)tk * DDIM + d0 + col] : 0.f;
        }
        __syncthreads();
        #pragma unroll
        for (int dd = 0; dd < DK; dd++) {
            float wv1 = w1p[(size_t)(d0 + dd) * HDIM + h0 + j];
            float wv2 = w2p[(size_t)(d0 + dd) * HDIM + h0 + j];
            #pragma unroll
            for (int r = 0; r < 16; r++) {
                float xv = xsh[i0 + 4 * r][dd];
                acc1[r] += xv * wv1;
                acc2[r] += xv * wv2;
            }
        }
    }

    #pragma unroll
    for (int r = 0; r < 16; r++) {
        int row = i0 + 4 * r;
        if (m0 + row < cnt) {
            float a = acc1[r];
            float hval = (a / (1.f + expf(-a))) * acc2[r];
            hidden[(size_t)(off + m0 + row) * HDIM + h0 + j] = hval;
        }
    }
}

// ---------------- Kernel 3: per-expert GEMM out = hidden @ w3, weighted scatter ----------------
// grid: (D/64, NTOK/TM capacity, NE), block 256
__global__ void k_ffn_out(const float* __restrict__ hidden,
                          const float* __restrict__ w3,
                          const int* __restrict__ counts,
                          const int* __restrict__ slot_token,
                          const float* __restrict__ slot_prob,
                          float* __restrict__ out) {
    int e = blockIdx.z;
    int cnt = counts[e];
    int m0 = blockIdx.y * TM;
    if (m0 >= cnt) return;
    int d0 = blockIdx.x * 64;
    int off = 0;
    for (int i = 0; i < e; i++) off += counts[i];

    int tid = threadIdx.x;
    int j = tid & 63;
    int i0 = tid >> 6;

    __shared__ float hsh[TM][DK];
    __shared__ int tok[TM];
    __shared__ float prb[TM];

    if (tid < TM) {
        int idx = m0 + tid;
        tok[tid] = (idx < cnt) ? slot_token[e * NTOK + idx] : -1;
        prb[tid] = (idx < cnt) ? slot_prob[e * NTOK + idx] : 0.f;
    }

    float acc[16];
    #pragma unroll
    for (int r = 0; r < 16; r++) acc[r] = 0.f;

    const float* w3p = w3 + (size_t)e * HDIM * DDIM;

    for (int h0 = 0; h0 < HDIM; h0 += DK) {
        __syncthreads();
        for (int t = tid; t < TM * DK; t += 256) {
            int row = t / DK, col = t % DK;
            hsh[row][col] = (m0 + row < cnt)
                ? hidden[(size_t)(off + m0 + row) * HDIM + h0 + col] : 0.f;
        }
        __syncthreads();
        #pragma unroll
        for (int hh = 0; hh < DK; hh++) {
            float wv = w3p[(size_t)(h0 + hh) * DDIM + d0 + j];
            #pragma unroll
            for (int r = 0; r < 16; r++) {
                acc[r] += hsh[i0 + 4 * r][hh] * wv;
            }
        }
    }

    #pragma unroll
    for (int r = 0; r < 16; r++) {
        int row = i0 + 4 * r;
        if (m0 + row < cnt) {
            atomicAdd(&out[(size_t)tok[row] * DDIM + d0 + j], acc[r] * prb[row]);
        }
    }
}

// ---------------- launch ----------------
extern "C" void kernel_launch(void* const* d_in, const int* in_sizes, int n_in,
                              void* d_out, int out_size, void* d_ws, size_t ws_size,
                              hipStream_t stream) {
    const float* x      = (const float*)d_in[0];
    const float* g      = (const float*)d_in[1];
    const float* gate_w = (const float*)d_in[2];
    const float* w1     = (const float*)d_in[3];
    const float* w2     = (const float*)d_in[4];
    const float* w3     = (const float*)d_in[5];
    float* out = (float*)d_out;

    // workspace layout
    char* ws = (char*)d_ws;
    int*   counts     = (int*)ws;                              ws += 256;               // E ints, padded
    int*   slot_token = (int*)ws;                              ws += NE * NTOK * 4;     // 64 KB
    float* slot_prob  = (float*)ws;                            ws += NE * NTOK * 4;     // 64 KB
    float* x_norm     = (float*)ws;                            ws += (size_t)NTOK * DDIM * 4;       // 8 MB
    float* hidden     = (float*)ws;                            ws += (size_t)NTOK * TOPK * HDIM * 4; // 32 MB

    hipMemsetAsync(counts, 0, 256, stream);
    hipMemsetAsync(out, 0, (size_t)NTOK * DDIM * sizeof(float), stream);

    k_norm_router<<<NTOK, 256, 0, stream>>>(x, g, gate_w, x_norm, counts, slot_token, slot_prob);

    dim3 grid_h(HDIM / TH, NTOK / TM, NE);
    k_ffn_h<<<grid_h, 256, 0, stream>>>(x_norm, w1, w2, counts, slot_token, hidden);

    dim3 grid_o(DDIM / 64, NTOK / TM, NE);
    k_ffn_out<<<grid_o, 256, 0, stream>>>(hidden, w3, counts, slot_token, slot_prob, out);
}

// Round 2
// 461.543 us; speedup vs baseline: 3.6648x; 3.6648x over previous
//
#include <hip/hip_runtime.h>
#include <math.h>

#define NTOK 2048      // B*S
#define DDIM 1024
#define HDIM 2048
#define NE 8
#define EPS_RMS 1e-5f
#define EPS_TOPK 1e-10f

#define AM 128         // M tile (tokens)
#define AN 64          // N tile
#define BK 32          // K tile == MFMA K
#define LSTR 40        // LDS row stride in ushorts (80 B: 16B-aligned, spreads banks)

typedef short short8 __attribute__((ext_vector_type(8)));
typedef float f32x4  __attribute__((ext_vector_type(4)));

__device__ inline unsigned pack2bf(float a, float b) {
    unsigned ua = __builtin_bit_cast(unsigned, a);
    unsigned ub = __builtin_bit_cast(unsigned, b);
    ua = (ua + 0x7fffu + ((ua >> 16) & 1u)) >> 16;
    ub = (ub + 0x7fffu + ((ub >> 16) & 1u)) & 0xffff0000u;
    return ua | ub;
}
__device__ inline unsigned short f2bf(float a) {
    unsigned ua = __builtin_bit_cast(unsigned, a);
    return (unsigned short)((ua + 0x7fffu + ((ua >> 16) & 1u)) >> 16);
}

// ---------------- Kernel 1: RMSNorm + router + top-2 scatter ----------------
__global__ void k_norm_router(const float* __restrict__ x,
                              const float* __restrict__ g,
                              const float* __restrict__ gate_w,
                              unsigned short* __restrict__ x_norm,   // bf16 out
                              int* __restrict__ counts,
                              int* __restrict__ slot_token,
                              float* __restrict__ slot_prob) {
    int token = blockIdx.x;
    int tid = threadIdx.x;
    int lane = tid & 63;
    int wave = tid >> 6;

    __shared__ float xs[DDIM];
    __shared__ float red[8];
    __shared__ float lr[4][NE];

    const float* xrow = x + (size_t)token * DDIM;
    float v[4];
    float ss = 0.f;
    #pragma unroll
    for (int i = 0; i < 4; i++) {
        float val = xrow[tid + i * 256];
        v[i] = val;
        ss += val * val;
    }
    #pragma unroll
    for (int off = 32; off > 0; off >>= 1) ss += __shfl_down(ss, off, 64);
    if (lane == 0) red[wave] = ss;
    __syncthreads();
    if (tid == 0) {
        float s = red[0] + red[1] + red[2] + red[3];
        red[0] = rsqrtf(s / (float)DDIM + EPS_RMS);
    }
    __syncthreads();
    float scale = red[0];
    #pragma unroll
    for (int i = 0; i < 4; i++) {
        int d = tid + i * 256;
        float xn = v[i] * scale * g[d];
        xs[d] = xn;
        x_norm[(size_t)token * DDIM + d] = f2bf(xn);
    }
    __syncthreads();

    float part[NE];
    #pragma unroll
    for (int e = 0; e < NE; e++) part[e] = 0.f;
    for (int d = tid; d < DDIM; d += 256) {
        float xv = xs[d];
        #pragma unroll
        for (int e = 0; e < NE; e++) part[e] += xv * gate_w[e * DDIM + d];
    }
    #pragma unroll
    for (int e = 0; e < NE; e++) {
        #pragma unroll
        for (int off = 32; off > 0; off >>= 1) part[e] += __shfl_down(part[e], off, 64);
    }
    if (lane == 0) {
        #pragma unroll
        for (int e = 0; e < NE; e++) lr[wave][e] = part[e];
    }
    __syncthreads();
    if (tid == 0) {
        float logits[NE];
        #pragma unroll
        for (int e = 0; e < NE; e++)
            logits[e] = lr[0][e] + lr[1][e] + lr[2][e] + lr[3][e];
        float mx = logits[0];
        #pragma unroll
        for (int e = 1; e < NE; e++) mx = fmaxf(mx, logits[e]);
        float p[NE];
        float Z = 0.f;
        #pragma unroll
        for (int e = 0; e < NE; e++) { p[e] = expf(logits[e] - mx); Z += p[e]; }
        #pragma unroll
        for (int e = 0; e < NE; e++) p[e] /= Z;
        int i1 = 0;
        #pragma unroll
        for (int e = 1; e < NE; e++) if (p[e] > p[i1]) i1 = e;
        int i2 = -1;
        #pragma unroll
        for (int e = 0; e < NE; e++) {
            if (e == i1) continue;
            if (i2 < 0 || p[e] > p[i2]) i2 = e;
        }
        float denom = p[i1] + p[i2] + EPS_TOPK;
        int pos1 = atomicAdd(&counts[i1], 1);
        slot_token[i1 * NTOK + pos1] = token;
        slot_prob[i1 * NTOK + pos1] = p[i1] / denom;
        int pos2 = atomicAdd(&counts[i2], 1);
        slot_token[i2 * NTOK + pos2] = token;
        slot_prob[i2 * NTOK + pos2] = p[i2] / denom;
    }
}

// ---------------- Kernel 2: per-expert MFMA GEMM h1,h2 + SiLU -> hidden(bf16) ----------------
// grid: (HDIM/AN, 2048/AM, NE), block 256 (4 waves)
__global__ __launch_bounds__(256) void k_ffn_h(
        const unsigned short* __restrict__ x_norm,  // bf16 [NTOK][D]
        const float* __restrict__ w1,               // [E][D][H]
        const float* __restrict__ w2,
        const int* __restrict__ counts,
        const int* __restrict__ slot_token,
        unsigned short* __restrict__ hidden) {      // bf16 [slots][H]
    int e = blockIdx.z;
    int cnt = counts[e];
    int m0 = blockIdx.y * AM;
    if (m0 >= cnt) return;
    int h0 = blockIdx.x * AN;
    int off = 0;
    for (int i = 0; i < e; i++) off += counts[i];

    int tid = threadIdx.x, lane = tid & 63, wv = tid >> 6;

    __shared__ unsigned short Ash[AM * LSTR];   // 10 KB
    __shared__ unsigned short B1s[AN * LSTR];   // 5 KB
    __shared__ unsigned short B2s[AN * LSTR];   // 5 KB
    __shared__ int tok[AM];

    if (tid < AM) {
        int idx = m0 + tid;
        tok[tid] = (idx < cnt) ? slot_token[e * NTOK + idx] : -1;
    }
    __syncthreads();

    int arow = tid >> 1, ahalf = tid & 1;
    int atok = tok[arow];
    int bn = tid & 63, bkg = tid >> 6;

    const float* w1p = w1 + (size_t)e * DDIM * HDIM + h0 + bn;
    const float* w2p = w2 + (size_t)e * DDIM * HDIM + h0 + bn;

    f32x4 acc1[2][4], acc2[2][4];
    #pragma unroll
    for (int i = 0; i < 2; i++)
        #pragma unroll
        for (int j = 0; j < 4; j++) {
            acc1[i][j] = (f32x4){0.f, 0.f, 0.f, 0.f};
            acc2[i][j] = (f32x4){0.f, 0.f, 0.f, 0.f};
        }

    int l15 = lane & 15, q4 = lane >> 4;

    for (int d0 = 0; d0 < DDIM; d0 += BK) {
        // issue global loads into registers first
        uint4 av0 = {0u,0u,0u,0u}, av1 = {0u,0u,0u,0u};
        if (atok >= 0) {
            const uint4* src = (const uint4*)(x_norm + (size_t)atok * DDIM + d0 + ahalf * 16);
            av0 = src[0];
            av1 = src[1];
        }
        unsigned b1v[4], b2v[4];
        #pragma unroll
        for (int q = 0; q < 4; q++) {
            int k0 = q * 8 + bkg * 2;
            float f0 = w1p[(size_t)(d0 + k0) * HDIM];
            float f1 = w1p[(size_t)(d0 + k0 + 1) * HDIM];
            b1v[q] = pack2bf(f0, f1);
            float g0 = w2p[(size_t)(d0 + k0) * HDIM];
            float g1 = w2p[(size_t)(d0 + k0 + 1) * HDIM];
            b2v[q] = pack2bf(g0, g1);
        }
        __syncthreads();
        *(uint4*)&Ash[arow * LSTR + ahalf * 16]     = av0;
        *(uint4*)&Ash[arow * LSTR + ahalf * 16 + 8] = av1;
        #pragma unroll
        for (int q = 0; q < 4; q++) {
            int k0 = q * 8 + bkg * 2;
            *(unsigned*)&B1s[bn * LSTR + k0] = b1v[q];
            *(unsigned*)&B2s[bn * LSTR + k0] = b2v[q];
        }
        __syncthreads();

        short8 a0 = *(const short8*)&Ash[(wv * 32 + l15) * LSTR + q4 * 8];
        short8 a1 = *(const short8*)&Ash[(wv * 32 + 16 + l15) * LSTR + q4 * 8];
        #pragma unroll
        for (int cf = 0; cf < 4; cf++) {
            short8 bb1 = *(const short8*)&B1s[(cf * 16 + l15) * LSTR + q4 * 8];
            short8 bb2 = *(const short8*)&B2s[(cf * 16 + l15) * LSTR + q4 * 8];
            acc1[0][cf] = __builtin_amdgcn_mfma_f32_16x16x32_bf16(a0, bb1, acc1[0][cf], 0, 0, 0);
            acc1[1][cf] = __builtin_amdgcn_mfma_f32_16x16x32_bf16(a1, bb1, acc1[1][cf], 0, 0, 0);
            acc2[0][cf] = __builtin_amdgcn_mfma_f32_16x16x32_bf16(a0, bb2, acc2[0][cf], 0, 0, 0);
            acc2[1][cf] = __builtin_amdgcn_mfma_f32_16x16x32_bf16(a1, bb2, acc2[1][cf], 0, 0, 0);
        }
    }

    // epilogue: silu(h1)*h2 -> hidden bf16. C layout: col=lane&15, row=quad*4+reg
    #pragma unroll
    for (int rf = 0; rf < 2; rf++) {
        int rowbase = wv * 32 + rf * 16 + q4 * 4;
        #pragma unroll
        for (int cf = 0; cf < 4; cf++) {
            int col = h0 + cf * 16 + l15;
            #pragma unroll
            for (int r = 0; r < 4; r++) {
                int row = m0 + rowbase + r;
                if (row < cnt) {
                    float a = acc1[rf][cf][r];
                    float hv = (a / (1.f + __expf(-a))) * acc2[rf][cf][r];
                    hidden[(size_t)(off + row) * HDIM + col] = f2bf(hv);
                }
            }
        }
    }
}

// ---------------- Kernel 3: per-expert MFMA GEMM hidden @ w3, weighted atomic scatter ----------------
// grid: (DDIM/AN, 2048/AM, NE), block 256
__global__ __launch_bounds__(256) void k_ffn_out(
        const unsigned short* __restrict__ hidden,  // bf16 [slots][H]
        const float* __restrict__ w3,               // [E][H][D]
        const int* __restrict__ counts,
        const int* __restrict__ slot_token,
        const float* __restrict__ slot_prob,
        float* __restrict__ out) {
    int e = blockIdx.z;
    int cnt = counts[e];
    int m0 = blockIdx.y * AM;
    if (m0 >= cnt) return;
    int d0 = blockIdx.x * AN;
    int off = 0;
    for (int i = 0; i < e; i++) off += counts[i];

    int tid = threadIdx.x, lane = tid & 63, wv = tid >> 6;

    __shared__ unsigned short Ash[AM * LSTR];
    __shared__ unsigned short B3s[AN * LSTR];
    __shared__ int tokL[AM];
    __shared__ float prbL[AM];

    if (tid < AM) {
        int idx = m0 + tid;
        tokL[tid] = (idx < cnt) ? slot_token[e * NTOK + idx] : -1;
        prbL[tid] = (idx < cnt) ? slot_prob[e * NTOK + idx] : 0.f;
    }
    __syncthreads();

    int arow = tid >> 1, ahalf = tid & 1;
    bool avalid = (m0 + arow) < cnt;
    int bn = tid & 63, bkg = tid >> 6;

    const float* w3p = w3 + (size_t)e * HDIM * DDIM + d0 + bn;

    f32x4 acc[2][4];
    #pragma unroll
    for (int i = 0; i < 2; i++)
        #pragma unroll
        for (int j = 0; j < 4; j++) acc[i][j] = (f32x4){0.f, 0.f, 0.f, 0.f};

    int l15 = lane & 15, q4 = lane >> 4;

    for (int h0 = 0; h0 < HDIM; h0 += BK) {
        uint4 av0 = {0u,0u,0u,0u}, av1 = {0u,0u,0u,0u};
        if (avalid) {
            const uint4* src = (const uint4*)(hidden + (size_t)(off + m0 + arow) * HDIM + h0 + ahalf * 16);
            av0 = src[0];
            av1 = src[1];
        }
        unsigned b3v[4];
        #pragma unroll
        for (int q = 0; q < 4; q++) {
            int k0 = q * 8 + bkg * 2;
            float f0 = w3p[(size_t)(h0 + k0) * DDIM];
            float f1 = w3p[(size_t)(h0 + k0 + 1) * DDIM];
            b3v[q] = pack2bf(f0, f1);
        }
        __syncthreads();
        *(uint4*)&Ash[arow * LSTR + ahalf * 16]     = av0;
        *(uint4*)&Ash[arow * LSTR + ahalf * 16 + 8] = av1;
        #pragma unroll
        for (int q = 0; q < 4; q++) {
            int k0 = q * 8 + bkg * 2;
            *(unsigned*)&B3s[bn * LSTR + k0] = b3v[q];
        }
        __syncthreads();

        short8 a0 = *(const short8*)&Ash[(wv * 32 + l15) * LSTR + q4 * 8];
        short8 a1 = *(const short8*)&Ash[(wv * 32 + 16 + l15) * LSTR + q4 * 8];
        #pragma unroll
        for (int cf = 0; cf < 4; cf++) {
            short8 bb = *(const short8*)&B3s[(cf * 16 + l15) * LSTR + q4 * 8];
            acc[0][cf] = __builtin_amdgcn_mfma_f32_16x16x32_bf16(a0, bb, acc[0][cf], 0, 0, 0);
            acc[1][cf] = __builtin_amdgcn_mfma_f32_16x16x32_bf16(a1, bb, acc[1][cf], 0, 0, 0);
        }
    }

    #pragma unroll
    for (int rf = 0; rf < 2; rf++) {
        int rowbase = wv * 32 + rf * 16 + q4 * 4;
        #pragma unroll
        for (int cf = 0; cf < 4; cf++) {
            int col = d0 + cf * 16 + l15;
            #pragma unroll
            for (int r = 0; r < 4; r++) {
                int rowl = rowbase + r;
                if (m0 + rowl < cnt) {
                    int tk = tokL[rowl];
                    float pv = prbL[rowl];
                    atomicAdd(&out[(size_t)tk * DDIM + col], acc[rf][cf][r] * pv);
                }
            }
        }
    }
}

// ---------------- launch ----------------
extern "C" void kernel_launch(void* const* d_in, const int* in_sizes, int n_in,
                              void* d_out, int out_size, void* d_ws, size_t ws_size,
                              hipStream_t stream) {
    const float* x      = (const float*)d_in[0];
    const float* g      = (const float*)d_in[1];
    const float* gate_w = (const float*)d_in[2];
    const float* w1     = (const float*)d_in[3];
    const float* w2     = (const float*)d_in[4];
    const float* w3     = (const float*)d_in[5];
    float* out = (float*)d_out;

    char* ws = (char*)d_ws;
    int*   counts     = (int*)ws;                 ws += 256;
    int*   slot_token = (int*)ws;                 ws += NE * NTOK * 4;
    float* slot_prob  = (float*)ws;               ws += NE * NTOK * 4;
    unsigned short* x_norm = (unsigned short*)ws; ws += (size_t)NTOK * DDIM * 2;        // 4 MB bf16
    unsigned short* hidden = (unsigned short*)ws; ws += (size_t)NTOK * 2 * HDIM * 2;    // 16 MB bf16

    hipMemsetAsync(counts, 0, 256, stream);
    hipMemsetAsync(out, 0, (size_t)NTOK * DDIM * sizeof(float), stream);

    k_norm_router<<<NTOK, 256, 0, stream>>>(x, g, gate_w, x_norm, counts, slot_token, slot_prob);

    dim3 grid_h(HDIM / AN, NTOK / AM, NE);
    k_ffn_h<<<grid_h, 256, 0, stream>>>(x_norm, w1, w2, counts, slot_token, hidden);

    dim3 grid_o(DDIM / AN, NTOK / AM, NE);
    k_ffn_out<<<grid_o, 256, 0, stream>>>(hidden, w3, counts, slot_token, slot_prob, out);
}

// Round 3
// 407.033 us; speedup vs baseline: 4.1556x; 1.1339x over previous
//
#include <hip/hip_runtime.h>
#include <math.h>

#define NTOK 2048      // B*S
#define DDIM 1024
#define HDIM 2048
#define NE 8
#define EPS_RMS 1e-5f
#define EPS_TOPK 1e-10f

#define AM 128         // M tile (tokens)
#define AN 64          // N tile
#define BK 32          // K tile == MFMA K
#define LSTR 40        // LDS row stride in ushorts (80 B)

typedef short short8 __attribute__((ext_vector_type(8)));
typedef float f32x4  __attribute__((ext_vector_type(4)));

__device__ inline unsigned pack2bf(float a, float b) {
    unsigned ua = __builtin_bit_cast(unsigned, a);
    unsigned ub = __builtin_bit_cast(unsigned, b);
    ua = (ua + 0x7fffu + ((ua >> 16) & 1u)) >> 16;
    ub = (ub + 0x7fffu + ((ub >> 16) & 1u)) & 0xffff0000u;
    return ua | ub;
}
__device__ inline unsigned short f2bf(float a) {
    unsigned ua = __builtin_bit_cast(unsigned, a);
    return (unsigned short)((ua + 0x7fffu + ((ua >> 16) & 1u)) >> 16);
}

// ---------------- Kernel 1: RMSNorm + router, one wave per token ----------------
// grid NTOK/4, block 256
__global__ __launch_bounds__(256) void k_norm_router(
        const float* __restrict__ x,
        const float* __restrict__ g,
        const float* __restrict__ gate_w,
        unsigned short* __restrict__ x_norm,
        int* __restrict__ counts,
        int* __restrict__ slot_token,
        float* __restrict__ slot_prob) {
    int lane = threadIdx.x & 63;
    int token = blockIdx.x * 4 + (threadIdx.x >> 6);
    const float* xrow = x + (size_t)token * DDIM;

    float v[16];
    float ss = 0.f;
    #pragma unroll
    for (int i = 0; i < 16; i++) {
        float t = xrow[lane + i * 64];
        v[i] = t;
        ss += t * t;
    }
    #pragma unroll
    for (int o = 32; o > 0; o >>= 1) ss += __shfl_down(ss, o, 64);
    float scale = rsqrtf(__shfl(ss, 0, 64) * (1.f / (float)DDIM) + EPS_RMS);

    float part[NE];
    #pragma unroll
    for (int e = 0; e < NE; e++) part[e] = 0.f;
    #pragma unroll
    for (int i = 0; i < 16; i++) {
        int d = lane + i * 64;
        float xn = v[i] * scale * g[d];
        x_norm[(size_t)token * DDIM + d] = f2bf(xn);
        #pragma unroll
        for (int e = 0; e < NE; e++) part[e] += xn * gate_w[e * DDIM + d];
    }
    #pragma unroll
    for (int e = 0; e < NE; e++) {
        #pragma unroll
        for (int o = 32; o > 0; o >>= 1) part[e] += __shfl_down(part[e], o, 64);
    }

    if (lane == 0) {
        float mx = part[0];
        #pragma unroll
        for (int e = 1; e < NE; e++) mx = fmaxf(mx, part[e]);
        float p[NE];
        float Z = 0.f;
        #pragma unroll
        for (int e = 0; e < NE; e++) { p[e] = __expf(part[e] - mx); Z += p[e]; }
        float rz = 1.f / Z;
        #pragma unroll
        for (int e = 0; e < NE; e++) p[e] *= rz;
        int i1 = 0;
        #pragma unroll
        for (int e = 1; e < NE; e++) if (p[e] > p[i1]) i1 = e;
        int i2 = -1;
        #pragma unroll
        for (int e = 0; e < NE; e++) {
            if (e == i1) continue;
            if (i2 < 0 || p[e] > p[i2]) i2 = e;
        }
        float denom = p[i1] + p[i2] + EPS_TOPK;
        int pos1 = atomicAdd(&counts[i1], 1);
        slot_token[i1 * NTOK + pos1] = token;
        slot_prob[i1 * NTOK + pos1] = p[i1] / denom;
        int pos2 = atomicAdd(&counts[i2], 1);
        slot_token[i2 * NTOK + pos2] = token;
        slot_prob[i2 * NTOK + pos2] = p[i2] / denom;
    }
}

// ---------------- Kernel 2: per-expert MFMA GEMM h1,h2 + SiLU -> hidden(bf16) ----------------
// grid: (HDIM/AN, NTOK/AM, NE), block 256
__global__ __launch_bounds__(256) void k_ffn_h(
        const unsigned short* __restrict__ x_norm,  // bf16 [NTOK][D]
        const float* __restrict__ w1,               // [E][D][H]
        const float* __restrict__ w2,
        const int* __restrict__ counts,
        const int* __restrict__ slot_token,
        unsigned short* __restrict__ hidden) {      // bf16 [slots][H]
    int e = blockIdx.z;
    int cnt = counts[e];
    int m0 = blockIdx.y * AM;
    if (m0 >= cnt) return;
    int h0 = blockIdx.x * AN;
    int off = 0;
    for (int i = 0; i < e; i++) off += counts[i];

    int tid = threadIdx.x, lane = tid & 63, wv = tid >> 6;

    __shared__ unsigned short Ash[AM * LSTR];   // 10 KB
    __shared__ unsigned short B1s[AN * LSTR];   // 5 KB
    __shared__ unsigned short B2s[AN * LSTR];   // 5 KB
    __shared__ int tok[AM];

    if (tid < AM) {
        int idx = m0 + tid;
        tok[tid] = (idx < cnt) ? slot_token[e * NTOK + idx] : -1;
    }
    __syncthreads();

    int arow = tid >> 1, ahalf = tid & 1;
    int atok = tok[arow];
    const unsigned short* aptr =
        (atok >= 0) ? (x_norm + (size_t)atok * DDIM + ahalf * 16) : nullptr;

    // B staging: wave wv loads k-rows wv*8..wv*8+7 for n = lane (conflict-free write)
    const float* w1p = w1 + (size_t)e * DDIM * HDIM + h0 + lane;
    const float* w2p = w2 + (size_t)e * DDIM * HDIM + h0 + lane;

    f32x4 acc1[2][4], acc2[2][4];
    #pragma unroll
    for (int i = 0; i < 2; i++)
        #pragma unroll
        for (int j = 0; j < 4; j++) {
            acc1[i][j] = (f32x4){0.f, 0.f, 0.f, 0.f};
            acc2[i][j] = (f32x4){0.f, 0.f, 0.f, 0.f};
        }

    int l15 = lane & 15, q4 = lane >> 4;

    uint4 av0 = {0u,0u,0u,0u}, av1 = {0u,0u,0u,0u};
    float b1f[8], b2f[8];

    // prologue: load chunk 0
    if (aptr) {
        const uint4* src = (const uint4*)aptr;
        av0 = src[0]; av1 = src[1];
    }
    #pragma unroll
    for (int i = 0; i < 8; i++) {
        b1f[i] = w1p[(size_t)(wv * 8 + i) * HDIM];
        b2f[i] = w2p[(size_t)(wv * 8 + i) * HDIM];
    }

    for (int d0 = 0; d0 < DDIM; d0 += BK) {
        __syncthreads();
        *(uint4*)&Ash[arow * LSTR + ahalf * 16]     = av0;
        *(uint4*)&Ash[arow * LSTR + ahalf * 16 + 8] = av1;
        {
            uint4 pb1, pb2;
            pb1.x = pack2bf(b1f[0], b1f[1]); pb1.y = pack2bf(b1f[2], b1f[3]);
            pb1.z = pack2bf(b1f[4], b1f[5]); pb1.w = pack2bf(b1f[6], b1f[7]);
            pb2.x = pack2bf(b2f[0], b2f[1]); pb2.y = pack2bf(b2f[2], b2f[3]);
            pb2.z = pack2bf(b2f[4], b2f[5]); pb2.w = pack2bf(b2f[6], b2f[7]);
            *(uint4*)&B1s[lane * LSTR + wv * 8] = pb1;
            *(uint4*)&B2s[lane * LSTR + wv * 8] = pb2;
        }
        __syncthreads();

        // prefetch next chunk into registers (overlaps the MFMA block below)
        int d1 = d0 + BK;
        if (d1 < DDIM) {
            if (aptr) {
                const uint4* src = (const uint4*)(aptr + d1);
                av0 = src[0]; av1 = src[1];
            }
            #pragma unroll
            for (int i = 0; i < 8; i++) {
                b1f[i] = w1p[(size_t)(d1 + wv * 8 + i) * HDIM];
                b2f[i] = w2p[(size_t)(d1 + wv * 8 + i) * HDIM];
            }
        }

        short8 a0 = *(const short8*)&Ash[(wv * 32 + l15) * LSTR + q4 * 8];
        short8 a1 = *(const short8*)&Ash[(wv * 32 + 16 + l15) * LSTR + q4 * 8];
        #pragma unroll
        for (int cf = 0; cf < 4; cf++) {
            short8 bb1 = *(const short8*)&B1s[(cf * 16 + l15) * LSTR + q4 * 8];
            short8 bb2 = *(const short8*)&B2s[(cf * 16 + l15) * LSTR + q4 * 8];
            acc1[0][cf] = __builtin_amdgcn_mfma_f32_16x16x32_bf16(a0, bb1, acc1[0][cf], 0, 0, 0);
            acc1[1][cf] = __builtin_amdgcn_mfma_f32_16x16x32_bf16(a1, bb1, acc1[1][cf], 0, 0, 0);
            acc2[0][cf] = __builtin_amdgcn_mfma_f32_16x16x32_bf16(a0, bb2, acc2[0][cf], 0, 0, 0);
            acc2[1][cf] = __builtin_amdgcn_mfma_f32_16x16x32_bf16(a1, bb2, acc2[1][cf], 0, 0, 0);
        }
    }

    // epilogue: silu(h1)*h2 -> hidden bf16. C layout: col=lane&15, row=quad*4+reg
    #pragma unroll
    for (int rf = 0; rf < 2; rf++) {
        int rowbase = wv * 32 + rf * 16 + q4 * 4;
        #pragma unroll
        for (int cf = 0; cf < 4; cf++) {
            int col = h0 + cf * 16 + l15;
            #pragma unroll
            for (int r = 0; r < 4; r++) {
                int row = m0 + rowbase + r;
                if (row < cnt) {
                    float a = acc1[rf][cf][r];
                    float hv = (a / (1.f + __expf(-a))) * acc2[rf][cf][r];
                    hidden[(size_t)(off + row) * HDIM + col] = f2bf(hv);
                }
            }
        }
    }
}

// ---------------- Kernel 3: per-expert MFMA GEMM hidden @ w3, K-split, atomic scatter ----------------
// grid: (DDIM/AN, NTOK/AM, NE*2), block 256
#define KSPLIT 2
#define KCH (HDIM / KSPLIT)
__global__ __launch_bounds__(256) void k_ffn_out(
        const unsigned short* __restrict__ hidden,  // bf16 [slots][H]
        const float* __restrict__ w3,               // [E][H][D]
        const int* __restrict__ counts,
        const int* __restrict__ slot_token,
        const float* __restrict__ slot_prob,
        float* __restrict__ out) {
    int e = blockIdx.z >> 1;
    int ks = blockIdx.z & 1;
    int cnt = counts[e];
    int m0 = blockIdx.y * AM;
    if (m0 >= cnt) return;
    int d0c = blockIdx.x * AN;
    int off = 0;
    for (int i = 0; i < e; i++) off += counts[i];
    int hbase = ks * KCH;

    int tid = threadIdx.x, lane = tid & 63, wv = tid >> 6;

    __shared__ unsigned short Ash[AM * LSTR];
    __shared__ unsigned short B3s[AN * LSTR];
    __shared__ int tokL[AM];
    __shared__ float prbL[AM];

    if (tid < AM) {
        int idx = m0 + tid;
        tokL[tid] = (idx < cnt) ? slot_token[e * NTOK + idx] : -1;
        prbL[tid] = (idx < cnt) ? slot_prob[e * NTOK + idx] : 0.f;
    }
    __syncthreads();

    int arow = tid >> 1, ahalf = tid & 1;
    bool avalid = (m0 + arow) < cnt;
    const unsigned short* aptr = avalid
        ? (hidden + (size_t)(off + m0 + arow) * HDIM + hbase + ahalf * 16) : nullptr;

    const float* w3p = w3 + (size_t)e * HDIM * DDIM + (size_t)hbase * DDIM + d0c + lane;

    f32x4 acc[2][4];
    #pragma unroll
    for (int i = 0; i < 2; i++)
        #pragma unroll
        for (int j = 0; j < 4; j++) acc[i][j] = (f32x4){0.f, 0.f, 0.f, 0.f};

    int l15 = lane & 15, q4 = lane >> 4;

    uint4 av0 = {0u,0u,0u,0u}, av1 = {0u,0u,0u,0u};
    float b3f[8];

    if (aptr) {
        const uint4* src = (const uint4*)aptr;
        av0 = src[0]; av1 = src[1];
    }
    #pragma unroll
    for (int i = 0; i < 8; i++)
        b3f[i] = w3p[(size_t)(wv * 8 + i) * DDIM];

    for (int h0 = 0; h0 < KCH; h0 += BK) {
        __syncthreads();
        *(uint4*)&Ash[arow * LSTR + ahalf * 16]     = av0;
        *(uint4*)&Ash[arow * LSTR + ahalf * 16 + 8] = av1;
        {
            uint4 pb;
            pb.x = pack2bf(b3f[0], b3f[1]); pb.y = pack2bf(b3f[2], b3f[3]);
            pb.z = pack2bf(b3f[4], b3f[5]); pb.w = pack2bf(b3f[6], b3f[7]);
            *(uint4*)&B3s[lane * LSTR + wv * 8] = pb;
        }
        __syncthreads();

        int h1 = h0 + BK;
        if (h1 < KCH) {
            if (aptr) {
                const uint4* src = (const uint4*)(aptr + h1);
                av0 = src[0]; av1 = src[1];
            }
            #pragma unroll
            for (int i = 0; i < 8; i++)
                b3f[i] = w3p[(size_t)(h1 + wv * 8 + i) * DDIM];
        }

        short8 a0 = *(const short8*)&Ash[(wv * 32 + l15) * LSTR + q4 * 8];
        short8 a1 = *(const short8*)&Ash[(wv * 32 + 16 + l15) * LSTR + q4 * 8];
        #pragma unroll
        for (int cf = 0; cf < 4; cf++) {
            short8 bb = *(const short8*)&B3s[(cf * 16 + l15) * LSTR + q4 * 8];
            acc[0][cf] = __builtin_amdgcn_mfma_f32_16x16x32_bf16(a0, bb, acc[0][cf], 0, 0, 0);
            acc[1][cf] = __builtin_amdgcn_mfma_f32_16x16x32_bf16(a1, bb, acc[1][cf], 0, 0, 0);
        }
    }

    #pragma unroll
    for (int rf = 0; rf < 2; rf++) {
        int rowbase = wv * 32 + rf * 16 + q4 * 4;
        #pragma unroll
        for (int cf = 0; cf < 4; cf++) {
            int col = d0c + cf * 16 + l15;
            #pragma unroll
            for (int r = 0; r < 4; r++) {
                int rowl = rowbase + r;
                if (m0 + rowl < cnt) {
                    int tk = tokL[rowl];
                    float pv = prbL[rowl];
                    atomicAdd(&out[(size_t)tk * DDIM + col], acc[rf][cf][r] * pv);
                }
            }
        }
    }
}

// ---------------- launch ----------------
extern "C" void kernel_launch(void* const* d_in, const int* in_sizes, int n_in,
                              void* d_out, int out_size, void* d_ws, size_t ws_size,
                              hipStream_t stream) {
    const float* x      = (const float*)d_in[0];
    const float* g      = (const float*)d_in[1];
    const float* gate_w = (const float*)d_in[2];
    const float* w1     = (const float*)d_in[3];
    const float* w2     = (const float*)d_in[4];
    const float* w3     = (const float*)d_in[5];
    float* out = (float*)d_out;

    char* ws = (char*)d_ws;
    int*   counts     = (int*)ws;                 ws += 256;
    int*   slot_token = (int*)ws;                 ws += NE * NTOK * 4;
    float* slot_prob  = (float*)ws;               ws += NE * NTOK * 4;
    unsigned short* x_norm = (unsigned short*)ws; ws += (size_t)NTOK * DDIM * 2;
    unsigned short* hidden = (unsigned short*)ws; ws += (size_t)NTOK * 2 * HDIM * 2;

    hipMemsetAsync(counts, 0, 256, stream);
    hipMemsetAsync(out, 0, (size_t)NTOK * DDIM * sizeof(float), stream);

    k_norm_router<<<NTOK / 4, 256, 0, stream>>>(x, g, gate_w, x_norm, counts, slot_token, slot_prob);

    dim3 grid_h(HDIM / AN, NTOK / AM, NE);
    k_ffn_h<<<grid_h, 256, 0, stream>>>(x_norm, w1, w2, counts, slot_token, hidden);

    dim3 grid_o(DDIM / AN, NTOK / AM, NE * KSPLIT);
    k_ffn_out<<<grid_o, 256, 0, stream>>>(hidden, w3, counts, slot_token, slot_prob, out);
}